// Round 3
// baseline (5837.157 us; speedup 1.0000x reference)
//
#include <hip/hip_runtime.h>
#include <stdint.h>

// UR-LSTM: B=128, T=512, I=512, H=512, OUT=256, 4H=2048
// Fast path: precompute x_proj[t][col][b] via MFMA GEMM; recurrence with
// W_hh in registers (16x16x32 MFMA tiles), LDS-staged h, flag-array barrier.
// Fallback (small ws): round-2 kernel (verified 5.18 ms).

#define NB 128
#define NT 512
#define NI 512
#define NH 512
#define NO 256

typedef short bf16x8 __attribute__((ext_vector_type(8)));
typedef unsigned short u16x4 __attribute__((ext_vector_type(4)));
typedef unsigned short u16x8 __attribute__((ext_vector_type(8)));
typedef unsigned int  u32x4 __attribute__((ext_vector_type(4)));
typedef float f32x4  __attribute__((ext_vector_type(4)));
typedef float f32x16 __attribute__((ext_vector_type(16)));

// ---- workspace layout (bytes) ----
static const size_t WS_FLAGS = 0;                  // 4 groups x 64 u32, zeroed
static const size_t WS_HBUF  = 4096;               // 2 x [128][512] u32 (hi|lo<<16)
static const size_t WS_HT    = 528384;             // [128][512] f32
static const size_t WS_WHH   = (size_t)1 << 20;    // 4 MB packed W_hh B-frags
static const size_t WS_WIH   = (size_t)5 << 20;    // 4 MB packed W_ih B-frags
static const size_t WS_XSP   = (size_t)16 << 20;   // xs hi/lo bf16 planes, 64 MiB each
static const size_t WS_XP    = (size_t)152 << 20;  // x_proj [t][2048][128]
static const size_t XP32_BYTES = 536870912ull;     // u32 packed hi/lo
static const size_t XP16_BYTES = 268435456ull;     // bf16 hi only
static const size_t WS_WPACK_FB = (size_t)1 << 20; // fallback round-2 pack

__device__ __forceinline__ unsigned short f2bf(float f) {
  unsigned u = __float_as_uint(f);
  unsigned r = u + 0x7FFFu + ((u >> 16) & 1u);   // RNE, inputs finite
  return (unsigned short)(r >> 16);
}
__device__ __forceinline__ float bf2f(unsigned short b) {
  return __uint_as_float(((unsigned)b) << 16);
}
__device__ __forceinline__ float sigm(float z) {
  z = fminf(30.f, fmaxf(-30.f, z));
  return 1.f / (1.f + __expf(-z));
}
__device__ __forceinline__ float tanh_(float z) {
  float az = fminf(fabsf(z), 40.f);
  float e = __expf(-2.f * az);
  float t = (1.f - e) / (1.f + e);
  return z < 0.f ? -t : t;
}

// ============================ FAST PATH ============================

// xs [b][t][i] f32 -> bf16 hi/lo planes, row = t*128+b (t-major for GEMM/xp)
__global__ void __launch_bounds__(256, 1)
cvt_xs(const float* __restrict__ xs, unsigned short* __restrict__ hi,
       unsigned short* __restrict__ lo) {
  size_t gid = (size_t)blockIdx.x * 256 + threadIdx.x;
  size_t e0 = gid * 8;
  int b = (int)(e0 >> 18);
  int t = (int)((e0 >> 9) & 511);
  int i = (int)(e0 & 511);
  float4 x0 = *(const float4*)(xs + e0);
  float4 x1 = *(const float4*)(xs + e0 + 4);
  float xv[8] = {x0.x, x0.y, x0.z, x0.w, x1.x, x1.y, x1.z, x1.w};
  u16x8 vh, vl;
  #pragma unroll
  for (int e = 0; e < 8; e++) {
    unsigned short hb = f2bf(xv[e]);
    vh[e] = hb;
    vl[e] = f2bf(xv[e] - bf2f(hb));
  }
  size_t ro = ((size_t)t * 128 + b) * 512 + i;
  *(u16x8*)(hi + ro) = vh;
  *(u16x8*)(lo + ro) = vl;
}

// Reordered col space: c = unit*4 + gate (gate 0..3 = f,r,u,o).
// W_hh B-frags for 16x16x32: [p64][ct2][s16][split2][lane64][8]
__global__ void __launch_bounds__(256, 1)
pack_whh_k(const float* __restrict__ Whh, unsigned short* __restrict__ wp) {
  int cid = blockIdx.x * 256 + threadIdx.x;   // 0..262143
  int l = cid & 63, split = (cid >> 6) & 1, s = (cid >> 7) & 15;
  int ct = (cid >> 11) & 1, p = cid >> 12;
  int cr = p * 32 + ct * 16 + (l & 15);
  int row = (cr & 3) * 512 + (cr >> 2);
  int k = s * 32 + (l >> 4) * 8;
  const float* src = Whh + (size_t)row * 512 + k;
  bf16x8 o;
  #pragma unroll
  for (int e = 0; e < 8; e++) {
    float v = src[e];
    unsigned short h = f2bf(v);
    o[e] = (short)((split == 0) ? h : f2bf(v - bf2f(h)));
  }
  *(bf16x8*)(wp + (size_t)cid * 8) = o;
}

// W_ih B-frags for 32x32x16: [ct64][s32][split2][lane64][8]
__global__ void __launch_bounds__(256, 1)
pack_wih_k(const float* __restrict__ Wih, unsigned short* __restrict__ wp) {
  int cid = blockIdx.x * 256 + threadIdx.x;   // 0..262143
  int l = cid & 63, split = (cid >> 6) & 1, s = (cid >> 7) & 31;
  int ct = cid >> 12;
  int cr = ct * 32 + (l & 31);
  int row = (cr & 3) * 512 + (cr >> 2);
  int k = s * 16 + (l >> 5) * 8;
  const float* src = Wih + (size_t)row * 512 + k;
  bf16x8 o;
  #pragma unroll
  for (int e = 0; e < 8; e++) {
    float v = src[e];
    unsigned short h = f2bf(v);
    o[e] = (short)((split == 0) ? h : f2bf(v - bf2f(h)));
  }
  *(bf16x8*)(wp + (size_t)cid * 8) = o;
}

// x_proj GEMM: rows bt'=t*128+b (64/WG), cols 2048 reordered, K=512 split-3.
// Output [t][col][128 b]: XP32 = u32 (hi|lo<<16), XP16 = bf16 hi.
template<bool XP16>
__global__ void __launch_bounds__(256, 1)
xproj_gemm(const unsigned short* __restrict__ xs_hi,
           const unsigned short* __restrict__ xs_lo,
           const unsigned short* __restrict__ wih,
           unsigned char* __restrict__ xpo) {
  extern __shared__ char smem[];
  unsigned short* Ahi = (unsigned short*)smem;      // [64][520]
  unsigned short* Alo = Ahi + 64 * 520;
  const int tid = threadIdx.x, wave = tid >> 6, lane = tid & 63;
  const int wr = wave >> 1, wc = wave & 1;
  const long bt0 = (long)blockIdx.x * 64;

  #pragma unroll
  for (int it = 0; it < 16; it++) {
    int f16 = it * 256 + tid;
    int row = f16 >> 6, c16 = (f16 & 63) * 8;
    size_t go = (size_t)(bt0 + row) * 512 + c16;
    *(u16x8*)(Ahi + row * 520 + c16) = *(const u16x8*)(xs_hi + go);
    *(u16x8*)(Alo + row * 520 + c16) = *(const u16x8*)(xs_lo + go);
  }
  __syncthreads();

  const int arow = (wr * 32 + (lane & 31)) * 520;
  const int kg = (lane >> 5) * 8;
  for (int cc = 0; cc < 8; cc++) {
    f32x16 acc[4] = {};
    #pragma unroll 4
    for (int s = 0; s < 32; s++) {
      bf16x8 Ah = *(const bf16x8*)(Ahi + arow + s * 16 + kg);
      bf16x8 Al = *(const bf16x8*)(Alo + arow + s * 16 + kg);
      #pragma unroll
      for (int j = 0; j < 4; j++) {
        int ctg = wc * 32 + cc * 4 + j;
        const unsigned short* bp = wih + (size_t)(ctg * 32 + s) * 1024 + lane * 8;
        bf16x8 Bh = *(const bf16x8*)bp;
        bf16x8 Bl = *(const bf16x8*)(bp + 512);
        acc[j] = __builtin_amdgcn_mfma_f32_32x32x16_bf16(Ah, Bh, acc[j], 0, 0, 0);
        acc[j] = __builtin_amdgcn_mfma_f32_32x32x16_bf16(Ah, Bl, acc[j], 0, 0, 0);
        acc[j] = __builtin_amdgcn_mfma_f32_32x32x16_bf16(Al, Bh, acc[j], 0, 0, 0);
      }
    }
    #pragma unroll
    for (int j = 0; j < 4; j++) {
      int colg = (wc * 32 + cc * 4 + j) * 32 + (lane & 31);
      #pragma unroll
      for (int qd = 0; qd < 4; qd++) {
        long btq = bt0 + wr * 32 + 8 * qd + 4 * (lane >> 5);
        int tt = (int)(btq >> 7);
        int bq = (int)(btq & 127);
        if (!XP16) {
          u32x4 o;
          #pragma unroll
          for (int jj = 0; jj < 4; jj++) {
            float v = acc[j][qd * 4 + jj];
            unsigned short hb = f2bf(v);
            o[jj] = (unsigned)hb | ((unsigned)f2bf(v - bf2f(hb)) << 16);
          }
          *(u32x4*)(xpo + (((size_t)tt * 2048 + colg) * 128 + bq) * 4) = o;
        } else {
          u16x4 o;
          #pragma unroll
          for (int jj = 0; jj < 4; jj++) o[jj] = f2bf(acc[j][qd * 4 + jj]);
          *(u16x4*)(xpo + (((size_t)tt * 2048 + colg) * 128 + bq) * 2) = o;
        }
      }
    }
  }
}

// Recurrence: 256 WGs = 4 row-groups (g = bid&3, 2-XCD confined) x 64 col-slices.
// Per WG: 2x2 waves of 16x16 tiles; W_hh frags in 128 VGPRs; h via LDS.
template<bool XP16>
__global__ void __launch_bounds__(256, 1)
urlstm_rec2(const unsigned short* __restrict__ whh,
            const unsigned char* __restrict__ xp,
            const float* __restrict__ bias, const float* __restrict__ fbias,
            unsigned char* __restrict__ ws) {
  extern __shared__ char smem[];
  unsigned short* Hhi = (unsigned short*)smem;      // [32][520]
  unsigned short* Hlo = Hhi + 32 * 520;
  const int tid = threadIdx.x, wave = tid >> 6, lane = tid & 63;
  const int rt = wave >> 1, ct = wave & 1;
  const int g = blockIdx.x & 3, p = blockIdx.x >> 2;
  unsigned int* flags = (unsigned int*)ws + g * 64;
  unsigned int* hbuf = (unsigned int*)(ws + WS_HBUF);
  float* hT = (float*)(ws + WS_HT);

  bf16x8 Wh[16], Wl[16];
  {
    const unsigned short* wb = whh + (size_t)(p * 2 + ct) * 16384 + lane * 8;
    #pragma unroll
    for (int s = 0; s < 16; s++) {
      Wh[s] = *(const bf16x8*)(wb + (size_t)s * 1024);
      Wl[s] = *(const bf16x8*)(wb + (size_t)s * 1024 + 512);
    }
  }

  const int cl = lane & 15, lg = lane >> 4;
  const int gate = cl & 3;
  const int u = p * 8 + ct * 4 + (cl >> 2);
  const int b0 = g * 32 + rt * 16 + lg * 4;
  const int col = p * 32 + ct * 16 + cl;
  const float bv = bias[gate * 512 + u];
  const float fbv = fbias[u];
  float c_st[4] = {0.f, 0.f, 0.f, 0.f};

  #pragma unroll 1
  for (int t = 0; t < NT; t++) {
    // prefetch x_proj (independent of recurrence)
    float xpv[4];
    if (XP16) {
      u16x4 w = *(const u16x4*)(xp + (((size_t)t * 2048 + col) * 128 + b0) * 2);
      #pragma unroll
      for (int q = 0; q < 4; q++) xpv[q] = bf2f(w[q]);
    } else {
      u32x4 w = *(const u32x4*)(xp + (((size_t)t * 2048 + col) * 128 + b0) * 4);
      #pragma unroll
      for (int q = 0; q < 4; q++)
        xpv[q] = bf2f((unsigned short)(w[q] & 0xffffu)) +
                 bf2f((unsigned short)(w[q] >> 16));
    }

    if (t > 0 && wave == 0) {           // wave-parallel flag poll
      unsigned tgt = (unsigned)t;
      int guard = 0;
      while (1) {
        unsigned v = __hip_atomic_load(flags + lane, __ATOMIC_RELAXED,
                                       __HIP_MEMORY_SCOPE_AGENT);
        if (__all((int)(v >= tgt))) break;
        if (++guard > (1 << 20)) break;  // fail loud, not hung
      }
    }
    __syncthreads();

    if (t > 0) {                         // coop h -> LDS (coherent 8B loads)
      unsigned long long* hin = (unsigned long long*)
          (hbuf + (size_t)(t & 1) * 65536 + g * 16384);
      #pragma unroll
      for (int cchunk = 0; cchunk < 16; cchunk++) {
        int flat = cchunk * 1024 + tid * 4;
        unsigned long long v0 = __hip_atomic_load(hin + (flat >> 1),
            __ATOMIC_RELAXED, __HIP_MEMORY_SCOPE_AGENT);
        unsigned long long v1 = __hip_atomic_load(hin + (flat >> 1) + 1,
            __ATOMIC_RELAXED, __HIP_MEMORY_SCOPE_AGENT);
        unsigned a0 = (unsigned)v0, a1 = (unsigned)(v0 >> 32);
        unsigned a2 = (unsigned)v1, a3 = (unsigned)(v1 >> 32);
        int row = flat >> 9, uu = flat & 511;
        u16x4 hi4 = {(unsigned short)a0, (unsigned short)a1,
                     (unsigned short)a2, (unsigned short)a3};
        u16x4 lo4 = {(unsigned short)(a0 >> 16), (unsigned short)(a1 >> 16),
                     (unsigned short)(a2 >> 16), (unsigned short)(a3 >> 16)};
        *(u16x4*)(Hhi + row * 520 + uu) = hi4;
        *(u16x4*)(Hlo + row * 520 + uu) = lo4;
      }
    }
    __syncthreads();

    f32x4 acc = {xpv[0], xpv[1], xpv[2], xpv[3]};
    if (t > 0) {
      const int ar = (rt * 16 + cl) * 520 + lg * 8;
      #pragma unroll
      for (int s = 0; s < 16; s++) {
        bf16x8 Ah = *(const bf16x8*)(Hhi + ar + s * 32);
        bf16x8 Al = *(const bf16x8*)(Hlo + ar + s * 32);
        acc = __builtin_amdgcn_mfma_f32_16x16x32_bf16(Ah, Wh[s], acc, 0, 0, 0);
        acc = __builtin_amdgcn_mfma_f32_16x16x32_bf16(Ah, Wl[s], acc, 0, 0, 0);
        acc = __builtin_amdgcn_mfma_f32_16x16x32_bf16(Al, Wh[s], acc, 0, 0, 0);
      }
    }

    unsigned hw[4];
    float hf[4];
    const int base4 = lane & ~3;
    #pragma unroll
    for (int q = 0; q < 4; q++) {
      float a = acc[q] + bv;
      float fv = __shfl(a, base4 + 0);
      float rv = __shfl(a, base4 + 1);
      float uv = __shfl(a, base4 + 2);
      float ov = __shfl(a, base4 + 3);
      float fg = sigm(fv + fbv);
      float rg = sigm(rv - fbv);
      float gg = 2.f * rg * fg + (1.f - 2.f * rg) * fg * fg;
      float cn = gg * c_st[q] + (1.f - gg) * tanh_(uv);
      float hn = sigm(ov) * tanh_(cn);
      c_st[q] = cn;
      hf[q] = hn;
      unsigned short hb = f2bf(hn);
      hw[q] = (unsigned)hb | ((unsigned)f2bf(hn - bf2f(hb)) << 16);
    }
    if ((lane & 3) == 0) {
      unsigned int* hout = hbuf + (size_t)((t + 1) & 1) * 65536;
      #pragma unroll
      for (int q = 0; q < 4; q++)
        __hip_atomic_store(hout + (size_t)(b0 + q) * 512 + u, hw[q],
                           __ATOMIC_RELAXED, __HIP_MEMORY_SCOPE_AGENT);
      if (t == NT - 1) {
        #pragma unroll
        for (int q = 0; q < 4; q++) hT[(size_t)(b0 + q) * 512 + u] = hf[q];
      }
    }
    if (t != NT - 1) {
      asm volatile("s_waitcnt vmcnt(0)" ::: "memory");
      __syncthreads();
      if (tid == 0)
        __hip_atomic_store(flags + p, (unsigned)(t + 1), __ATOMIC_RELAXED,
                           __HIP_MEMORY_SCOPE_AGENT);
    }
  }
}

__global__ void __launch_bounds__(256, 1)
out_proj2(const unsigned char* __restrict__ ws, const float* __restrict__ Wout,
          const float* __restrict__ bout, float* __restrict__ out) {
  __shared__ float hrow[512];
  const float* hT = (const float*)(ws + WS_HT);
  const int b = blockIdx.x;
  const int o = threadIdx.x;
  for (int i = o; i < 512; i += 256) hrow[i] = hT[(size_t)b * 512 + i];
  __syncthreads();
  float acc = bout[o];
  const float4* w = (const float4*)(Wout + (size_t)o * 512);
  #pragma unroll 8
  for (int i = 0; i < 128; i++) {
    float4 wv = w[i];
    acc += hrow[4*i] * wv.x + hrow[4*i+1] * wv.y + hrow[4*i+2] * wv.z + hrow[4*i+3] * wv.w;
  }
  out[(size_t)b * 256 + o] = acc;
}

// ============================ FALLBACK (round-2, verified) ============================

__global__ void __launch_bounds__(256, 1)
pack_w_fb(const float* __restrict__ Wih, const float* __restrict__ Whh,
          unsigned short* __restrict__ wp) {
  int cid = blockIdx.x * 256 + threadIdx.x;
  int col   = cid & 31;
  int kg    = (cid >> 5) & 1;
  int split = (cid >> 6) & 1;
  int s     = (cid >> 7) & 63;
  int p     = cid >> 13;
  int k     = s * 16 + kg * 8;
  int gcol  = (col >> 3) * 512 + p * 8 + (col & 7);
  const float* src = (k < 512) ? (Whh + (size_t)gcol * 512 + k)
                               : (Wih + (size_t)gcol * 512 + (k - 512));
  bf16x8 o;
  #pragma unroll
  for (int i = 0; i < 8; i++) {
    float v = src[i];
    unsigned short h = f2bf(v);
    o[i] = (short)((split == 0) ? h : f2bf(v - bf2f(h)));
  }
  *(bf16x8*)(wp + (size_t)cid * 8) = o;
}

__global__ void __launch_bounds__(256, 1)
urlstm_rec_fb(const float* __restrict__ xs, const float* __restrict__ bias,
              const float* __restrict__ fbias, unsigned char* __restrict__ ws) {
  extern __shared__ char smem[];
  unsigned short* Wlds = (unsigned short*)smem;
  float* red = (float*)(smem + 131072);

  const int tid  = threadIdx.x;
  const int wave = tid >> 6;
  const int lane = tid & 63;
  const int lrow = lane & 31;
  const int half = lane >> 5;
  const int g = blockIdx.x >> 6;
  const int p = blockIdx.x & 63;

  unsigned int* cnt = (unsigned int*)(ws + (size_t)g * 256);
  const unsigned short* wpg = (const unsigned short*)(ws + WS_WPACK_FB) + (size_t)p * 65536;

  {
    const float4* srcv = (const float4*)wpg;
    float4* dstv = (float4*)Wlds;
    for (int i = tid; i < 8192; i += 256) dstv[i] = srcv[i];
  }

  const int col = lane & 31;
  const int j   = lane & 7;
  const int jg  = p * 8 + j;
  const float biasv = bias[(col >> 3) * 512 + p * 8 + (col & 7)];
  const float fbv   = fbias[jg];

  unsigned int* hbuf = (unsigned int*)(ws + WS_HBUF);
  const int grow0 = g * 32;
  const int arow  = grow0 + lrow;

  float c_st[4] = {0.f, 0.f, 0.f, 0.f};

  __syncthreads();

  #pragma unroll 1
  for (int t = 0; t < NT; t++) {
    f32x16 accx = {};
    if (wave >= 2) {
      #pragma unroll 4
      for (int kk = 0; kk < 16; kk++) {
        const int s = 32 + (wave - 2) * 16 + kk;
        const int i0 = s * 16 + half * 8 - 512;
        const float* xp = xs + ((size_t)arow * NT + t) * NI + i0;
        float4 x0 = *(const float4*)xp;
        float4 x1 = *(const float4*)(xp + 4);
        float xv[8] = {x0.x, x0.y, x0.z, x0.w, x1.x, x1.y, x1.z, x1.w};
        bf16x8 Ah, Al;
        #pragma unroll
        for (int e = 0; e < 8; e++) {
          unsigned short hb = f2bf(xv[e]);
          Ah[e] = (short)hb;
          Al[e] = (short)f2bf(xv[e] - bf2f(hb));
        }
        const unsigned short* bp = Wlds + (size_t)(s * 2) * 512 + lane * 8;
        bf16x8 Bh = *(const bf16x8*)bp;
        bf16x8 Bl = *(const bf16x8*)(bp + 512);
        accx = __builtin_amdgcn_mfma_f32_32x32x16_bf16(Ah, Bh, accx, 0, 0, 0);
        accx = __builtin_amdgcn_mfma_f32_32x32x16_bf16(Ah, Bl, accx, 0, 0, 0);
        accx = __builtin_amdgcn_mfma_f32_32x32x16_bf16(Al, Bh, accx, 0, 0, 0);
      }
    } else if (tid == 0 && t > 0) {
      const unsigned target = 64u * (unsigned)t;
      int guard = 0;
      while (__hip_atomic_load(cnt, __ATOMIC_RELAXED, __HIP_MEMORY_SCOPE_AGENT) < target) {
        if (++guard > (1 << 22)) break;
      }
    }
    __syncthreads();

    f32x16 acch = {};
    if (t > 0) {
      const unsigned int* hin = hbuf + (size_t)(t & 1) * 65536;
      unsigned int hv[64];
      #pragma unroll
      for (int kk = 0; kk < 8; kk++) {
        const int k = wave * 128 + kk * 16 + half * 8;
        #pragma unroll
        for (int e = 0; e < 8; e++)
          hv[kk * 8 + e] = __hip_atomic_load(
              (unsigned int*)(hin + (size_t)(k + e) * 128 + arow),
              __ATOMIC_RELAXED, __HIP_MEMORY_SCOPE_AGENT);
      }
      #pragma unroll
      for (int kk = 0; kk < 8; kk++) {
        bf16x8 Ah, Al;
        #pragma unroll
        for (int e = 0; e < 8; e++) {
          unsigned int w = hv[kk * 8 + e];
          Ah[e] = (short)(w & 0xffffu);
          Al[e] = (short)(w >> 16);
        }
        const int s = wave * 8 + kk;
        const unsigned short* bp = Wlds + (size_t)(s * 2) * 512 + lane * 8;
        bf16x8 Bh = *(const bf16x8*)bp;
        bf16x8 Bl = *(const bf16x8*)(bp + 512);
        acch = __builtin_amdgcn_mfma_f32_32x32x16_bf16(Ah, Bh, acch, 0, 0, 0);
        acch = __builtin_amdgcn_mfma_f32_32x32x16_bf16(Ah, Bl, acch, 0, 0, 0);
        acch = __builtin_amdgcn_mfma_f32_32x32x16_bf16(Al, Bh, acch, 0, 0, 0);
      }
    }

    {
      float* rh = red + (size_t)wave * 1024;
      #pragma unroll
      for (int r = 0; r < 16; r++) rh[r * 64 + lane] = acch[r];
      if (wave >= 2) {
        float* rx = red + (size_t)(2 + wave) * 1024;
        #pragma unroll
        for (int r = 0; r < 16; r++) rx[r * 64 + lane] = accx[r];
      }
    }
    __syncthreads();

    const int r0 = wave * 4;
    f32x4 sum = {};
    #pragma unroll
    for (int st = 0; st < 6; st++) {
      #pragma unroll
      for (int q = 0; q < 4; q++)
        sum[q] += red[(size_t)st * 1024 + (r0 + q) * 64 + lane];
    }

    unsigned int* hout = hbuf + (size_t)((t + 1) & 1) * 65536;
    const bool writer = (col < 8);
    const int srcbase = (lane & 32) | j;

    #pragma unroll
    for (int q = 0; q < 4; q++) {
      float a = sum[q] + biasv;
      float fv = __shfl(a, srcbase);
      float rv = __shfl(a, srcbase + 8);
      float uv = __shfl(a, srcbase + 16);
      float ov = __shfl(a, srcbase + 24);
      float fg = sigm(fv + fbv);
      float rg = sigm(rv - fbv);
      float gg = 2.f * rg * fg + (1.f - 2.f * rg) * fg * fg;
      float cn = gg * c_st[q] + (1.f - gg) * tanh_(uv);
      float hn = sigm(ov) * tanh_(cn);
      c_st[q] = cn;
      if (writer) {
        int row = grow0 + q + 8 * wave + 4 * half;
        unsigned short hb = f2bf(hn);
        unsigned int pw = (unsigned)hb | ((unsigned)f2bf(hn - bf2f(hb)) << 16);
        __hip_atomic_store(hout + (size_t)jg * 128 + row, pw,
                           __ATOMIC_RELAXED, __HIP_MEMORY_SCOPE_AGENT);
      }
    }

    if (t != NT - 1) {
      asm volatile("s_waitcnt vmcnt(0)" ::: "memory");
      __syncthreads();
      if (tid == 0)
        __hip_atomic_fetch_add(cnt, 1u, __ATOMIC_RELAXED, __HIP_MEMORY_SCOPE_AGENT);
    }
  }
}

__global__ void __launch_bounds__(256, 1)
out_proj_fb(const unsigned char* __restrict__ ws, const float* __restrict__ Wout,
            const float* __restrict__ bout, float* __restrict__ out) {
  __shared__ float hrow[512];
  const unsigned int* hT = (const unsigned int*)(ws + WS_HBUF);
  const int b = blockIdx.x;
  const int o = threadIdx.x;
  for (int i = o; i < 512; i += 256) {
    unsigned int w = hT[(size_t)i * 128 + b];
    hrow[i] = bf2f((unsigned short)(w & 0xffffu)) + bf2f((unsigned short)(w >> 16));
  }
  __syncthreads();
  float acc = bout[o];
  const float4* w = (const float4*)(Wout + (size_t)o * 512);
  #pragma unroll 8
  for (int i = 0; i < 128; i++) {
    float4 wv = w[i];
    acc += hrow[4*i] * wv.x + hrow[4*i+1] * wv.y + hrow[4*i+2] * wv.z + hrow[4*i+3] * wv.w;
  }
  out[(size_t)b * 256 + o] = acc;
}

// ============================ LAUNCH ============================

extern "C" void kernel_launch(void* const* d_in, const int* in_sizes, int n_in,
                              void* d_out, int out_size, void* d_ws, size_t ws_size,
                              hipStream_t stream) {
  const float* xs   = (const float*)d_in[0];
  const float* Wih  = (const float*)d_in[1];
  const float* Whh  = (const float*)d_in[2];
  const float* bias = (const float*)d_in[3];
  const float* fb   = (const float*)d_in[4];
  const float* Wout = (const float*)d_in[5];
  const float* bout = (const float*)d_in[6];
  unsigned char* ws = (unsigned char*)d_ws;
  float* out = (float*)d_out;

  hipMemsetAsync(ws, 0, 4096, stream);   // flags / counters

  const size_t need32 = WS_XP + XP32_BYTES;
  const size_t need16 = WS_XP + XP16_BYTES;

  if (ws_size >= need16) {
    unsigned short* xhi = (unsigned short*)(ws + WS_XSP);
    unsigned short* xlo = (unsigned short*)(ws + WS_XSP + 67108864ull);
    unsigned short* whhp = (unsigned short*)(ws + WS_WHH);
    unsigned short* wihp = (unsigned short*)(ws + WS_WIH);
    unsigned char* xpo = ws + WS_XP;

    cvt_xs<<<16384, 256, 0, stream>>>(xs, xhi, xlo);
    pack_whh_k<<<1024, 256, 0, stream>>>(Whh, whhp);
    pack_wih_k<<<1024, 256, 0, stream>>>(Wih, wihp);
    if (ws_size >= need32) {
      xproj_gemm<false><<<1024, 256, 133120, stream>>>(xhi, xlo, wihp, xpo);
      urlstm_rec2<false><<<256, 256, 66560, stream>>>(whhp, xpo, bias, fb, ws);
    } else {
      xproj_gemm<true><<<1024, 256, 133120, stream>>>(xhi, xlo, wihp, xpo);
      urlstm_rec2<true><<<256, 256, 66560, stream>>>(whhp, xpo, bias, fb, ws);
    }
    out_proj2<<<128, 256, 0, stream>>>(ws, Wout, bout, out);
  } else {
    pack_w_fb<<<2048, 256, 0, stream>>>(Wih, Whh, (unsigned short*)(ws + WS_WPACK_FB));
    urlstm_rec_fb<<<256, 256, 155648, stream>>>(xs, bias, fb, ws);
    out_proj_fb<<<128, 256, 0, stream>>>(ws, Wout, bout, out);
  }
}

// Round 4
// 3378.303 us; speedup vs baseline: 1.7278x; 1.7278x over previous
//
#include <hip/hip_runtime.h>
#include <stdint.h>

// UR-LSTM: B=128, T=512, I=512, H=512, OUT=256, 4H=2048
// xproj precompute (MFMA, coalesced store via LDS transpose) +
// persistent recurrence: 8 row-groups x 16 rows, 32 col-slices x 16 units.
// h exchange: 16B coherent (sc0 sc1) burst loads; flag-array barrier.

#define NT 512

typedef short bf16x8 __attribute__((ext_vector_type(8)));
typedef unsigned short u16x8 __attribute__((ext_vector_type(8)));
typedef unsigned int  u32x2 __attribute__((ext_vector_type(2)));
typedef unsigned int  u32x4 __attribute__((ext_vector_type(4)));
typedef float f32x4  __attribute__((ext_vector_type(4)));
typedef float f32x16 __attribute__((ext_vector_type(16)));

// ---- workspace layout (bytes) ----
static const size_t WS_HBUF = 4096;                // 2 x [128][512] u32 (hi|lo<<16)
static const size_t WS_HT   = 4096 + 524288;       // [128][512] f32
static const size_t WS_WHH  = (size_t)1 << 20;     // 4 MB packed W_hh B-frags
static const size_t WS_WIH  = (size_t)5 << 20;     // 4 MB packed W_ih B-frags
static const size_t WS_XP   = (size_t)16 << 20;    // x_proj [t][b][2048]
static const size_t XP32_BYTES = 536870912ull;     // u32 (hi|lo<<16)

__device__ __forceinline__ unsigned short f2bf(float f) {
  unsigned u = __float_as_uint(f);
  unsigned r = u + 0x7FFFu + ((u >> 16) & 1u);   // RNE, inputs finite
  return (unsigned short)(r >> 16);
}
__device__ __forceinline__ float bf2f(unsigned short b) {
  return __uint_as_float(((unsigned)b) << 16);
}
__device__ __forceinline__ float sigm(float z) {
  z = fminf(30.f, fmaxf(-30.f, z));
  return 1.f / (1.f + __expf(-z));
}
__device__ __forceinline__ float tanh_(float z) {
  float az = fminf(fabsf(z), 40.f);
  float e = __expf(-2.f * az);
  float t = (1.f - e) / (1.f + e);
  return z < 0.f ? -t : t;
}

// Reordered gate-col space: c = unit*4 + gate (gate 0..3 = f,r,u,o).
// W_hh B-frags (16x16x32): [P2=128][s16][split2][lane64][8]; P2 covers 16 cols.
__global__ void __launch_bounds__(256, 1)
pack_whh_k(const float* __restrict__ Whh, unsigned short* __restrict__ wp) {
  int cid = blockIdx.x * 256 + threadIdx.x;   // 0..262143
  int l = cid & 63, split = (cid >> 6) & 1, s = (cid >> 7) & 15;
  int cr = (cid >> 11) * 16 + (l & 15);
  int row = (cr & 3) * 512 + (cr >> 2);
  int k = s * 32 + (l >> 4) * 8;
  const float* src = Whh + (size_t)row * 512 + k;
  bf16x8 o;
  #pragma unroll
  for (int e = 0; e < 8; e++) {
    float v = src[e];
    unsigned short h = f2bf(v);
    o[e] = (short)((split == 0) ? h : f2bf(v - bf2f(h)));
  }
  *(bf16x8*)(wp + (size_t)cid * 8) = o;
}

// W_ih B-frags (32x32x16): [ct64][s32][split2][lane64][8]
__global__ void __launch_bounds__(256, 1)
pack_wih_k(const float* __restrict__ Wih, unsigned short* __restrict__ wp) {
  int cid = blockIdx.x * 256 + threadIdx.x;   // 0..262143
  int l = cid & 63, split = (cid >> 6) & 1, s = (cid >> 7) & 31;
  int ct = cid >> 12;
  int cr = ct * 32 + (l & 31);
  int row = (cr & 3) * 512 + (cr >> 2);
  int k = s * 16 + (l >> 5) * 8;
  const float* src = Wih + (size_t)row * 512 + k;
  bf16x8 o;
  #pragma unroll
  for (int e = 0; e < 8; e++) {
    float v = src[e];
    unsigned short h = f2bf(v);
    o[e] = (short)((split == 0) ? h : f2bf(v - bf2f(h)));
  }
  *(bf16x8*)(wp + (size_t)cid * 8) = o;
}

// x_proj GEMM: per WG fixed t, 64 b-rows; xs read f32 + split on the fly.
// Output coalesced (LDS transpose): xp[t][b][2048 cols] (u32 hi|lo or u16 hi).
template<bool XP16>
__global__ void __launch_bounds__(256, 1)
xproj_gemm(const float* __restrict__ xs,
           const unsigned short* __restrict__ wih,
           unsigned char* __restrict__ xpo) {
  extern __shared__ char smem[];
  unsigned short* Ahi = (unsigned short*)smem;              // [64][520]
  unsigned short* Alo = Ahi + 64 * 520;                     // [64][520]
  float* xT = (float*)(smem + 2 * 64 * 520 * 2);            // 4 x [32][36]
  const int tid = threadIdx.x, wave = tid >> 6, lane = tid & 63;
  const int wr = wave >> 1, wc = wave & 1;
  const int t = blockIdx.x >> 1;
  const int b0 = (blockIdx.x & 1) * 64;

  #pragma unroll
  for (int it = 0; it < 16; it++) {
    int f16 = it * 256 + tid;
    int r = f16 >> 6, c16 = (f16 & 63) * 8;
    const float* src = xs + ((size_t)(b0 + r) * 512 + t) * 512 + c16;
    float4 x0 = *(const float4*)src;
    float4 x1 = *(const float4*)(src + 4);
    float xv[8] = {x0.x, x0.y, x0.z, x0.w, x1.x, x1.y, x1.z, x1.w};
    u16x8 vh, vl;
    #pragma unroll
    for (int e = 0; e < 8; e++) {
      unsigned short hb = f2bf(xv[e]);
      vh[e] = hb;
      vl[e] = f2bf(xv[e] - bf2f(hb));
    }
    *(u16x8*)(Ahi + r * 520 + c16) = vh;
    *(u16x8*)(Alo + r * 520 + c16) = vl;
  }
  __syncthreads();

  const int arow = (wr * 32 + (lane & 31)) * 520;
  const int kg = (lane >> 5) * 8;
  const int half = lane >> 5, colw = lane & 31;
  float* xtw = xT + wave * 1152;
  const int trow = lane >> 1, tc0 = (lane & 1) * 16;

  for (int cc = 0; cc < 8; cc++) {
    f32x16 acc[4] = {};
    #pragma unroll 4
    for (int s = 0; s < 32; s++) {
      bf16x8 Ah = *(const bf16x8*)(Ahi + arow + s * 16 + kg);
      bf16x8 Al = *(const bf16x8*)(Alo + arow + s * 16 + kg);
      #pragma unroll
      for (int j = 0; j < 4; j++) {
        const int ctg = wc * 32 + cc * 4 + j;
        const unsigned short* bp = wih + (size_t)(ctg * 32 + s) * 1024 + lane * 8;
        bf16x8 Bh = *(const bf16x8*)bp;
        bf16x8 Bl = *(const bf16x8*)(bp + 512);
        acc[j] = __builtin_amdgcn_mfma_f32_32x32x16_bf16(Ah, Bh, acc[j], 0, 0, 0);
        acc[j] = __builtin_amdgcn_mfma_f32_32x32x16_bf16(Ah, Bl, acc[j], 0, 0, 0);
        acc[j] = __builtin_amdgcn_mfma_f32_32x32x16_bf16(Al, Bh, acc[j], 0, 0, 0);
      }
    }
    #pragma unroll
    for (int j = 0; j < 4; j++) {
      const int ctg = wc * 32 + cc * 4 + j;
      // C frag (32x32): col = lane&31, row = jj + 8*qd + 4*half -> LDS transpose
      #pragma unroll
      for (int qd = 0; qd < 4; qd++)
        #pragma unroll
        for (int jj = 0; jj < 4; jj++)
          xtw[(jj + 8 * qd + 4 * half) * 36 + colw] = acc[j][qd * 4 + jj];
      // same-wave LDS RAW: in-order DS pipe + compiler lgkm waits
      const int b = b0 + wr * 32 + trow;
      const size_t obase = ((size_t)t * 128 + b) * 2048 + (size_t)ctg * 32 + tc0;
      if (!XP16) {
        unsigned int ov[16];
        #pragma unroll
        for (int i2 = 0; i2 < 16; i2++) {
          float v = xtw[trow * 36 + tc0 + i2];
          unsigned short hb = f2bf(v);
          ov[i2] = (unsigned)hb | ((unsigned)f2bf(v - bf2f(hb)) << 16);
        }
        unsigned int* op = (unsigned int*)xpo + obase;
        #pragma unroll
        for (int i2 = 0; i2 < 4; i2++) {
          u32x4 o4 = {ov[i2*4], ov[i2*4+1], ov[i2*4+2], ov[i2*4+3]};
          *(u32x4*)(op + i2 * 4) = o4;
        }
      } else {
        unsigned short ov[16];
        #pragma unroll
        for (int i2 = 0; i2 < 16; i2++)
          ov[i2] = f2bf(xtw[trow * 36 + tc0 + i2]);
        unsigned short* op = (unsigned short*)xpo + obase;
        #pragma unroll
        for (int i2 = 0; i2 < 2; i2++) {
          u16x8 o8 = {ov[i2*8], ov[i2*8+1], ov[i2*8+2], ov[i2*8+3],
                      ov[i2*8+4], ov[i2*8+5], ov[i2*8+6], ov[i2*8+7]};
          *(u16x8*)(op + i2 * 8) = o8;
        }
      }
    }
  }
}

// Recurrence: 256 WGs = 8 row-groups (g = bid&7, 16 rows) x 32 col-slices
// (p = bid>>3, 16 units). 4 waves = 4 col-tiles of 16 cols; W_hh in VGPRs.
template<bool XP16>
__global__ void __launch_bounds__(256, 1)
urlstm_rec2(const unsigned short* __restrict__ whh,
            const unsigned char* __restrict__ xp,
            const float* __restrict__ bias, const float* __restrict__ fbias,
            unsigned char* __restrict__ ws) {
  extern __shared__ char smem[];
  unsigned short* Hhi = (unsigned short*)smem;        // [16][520]
  unsigned short* Hlo = Hhi + 16 * 520;               // [16][520]
  const int tid = threadIdx.x, wave = tid >> 6, lane = tid & 63;
  const int ct = wave;                 // col-tile 0..3
  const int g = blockIdx.x & 7, p = blockIdx.x >> 3;
  unsigned int* flags = (unsigned int*)ws + g * 64;   // 32 used, 256B stride
  unsigned int* hbuf = (unsigned int*)(ws + WS_HBUF);
  float* hT = (float*)(ws + WS_HT);

  // resident W_hh fragments: 16 K-slices x (hi,lo) = 128 VGPRs
  bf16x8 Wh[16], Wl[16];
  {
    const unsigned short* wb = whh + (size_t)(p * 4 + ct) * 16384 + lane * 8;
    #pragma unroll
    for (int s = 0; s < 16; s++) {
      Wh[s] = *(const bf16x8*)(wb + (size_t)s * 1024);
      Wl[s] = *(const bf16x8*)(wb + (size_t)s * 1024 + 512);
    }
  }

  const int cl = lane & 15, lg = lane >> 4;
  const int gate = cl & 3;
  const int u = p * 16 + ct * 4 + (cl >> 2);   // global hidden unit
  const int b0 = g * 16 + lg * 4;              // C rows: b0+q
  const int col = p * 64 + ct * 16 + cl;       // global gate-col
  const float bv = bias[gate * 512 + u];
  const float fbv = fbias[u];
  const int ar = cl * 520 + lg * 8;            // A-frag LDS base
  float c_st[4] = {0.f, 0.f, 0.f, 0.f};

  #pragma unroll 1
  for (int t = 0; t < NT; t++) {
    // x_proj prefetch (independent of recurrence)
    float xpv[4];
    if (XP16) {
      const unsigned short* xp16 = (const unsigned short*)xp;
      #pragma unroll
      for (int q = 0; q < 4; q++)
        xpv[q] = bf2f(xp16[((size_t)t * 128 + b0 + q) * 2048 + col]);
    } else {
      const unsigned int* xp32 = (const unsigned int*)xp;
      #pragma unroll
      for (int q = 0; q < 4; q++) {
        unsigned int w = xp32[((size_t)t * 128 + b0 + q) * 2048 + col];
        xpv[q] = bf2f((unsigned short)(w & 0xffffu)) +
                 bf2f((unsigned short)(w >> 16));
      }
    }

    if (t > 0) {
      if (wave == 0) {                 // wave-parallel flag poll (32 producers)
        unsigned tgt = (unsigned)t;
        int guard = 0;
        while (1) {
          unsigned v = __hip_atomic_load(flags + (lane & 31), __ATOMIC_RELAXED,
                                         __HIP_MEMORY_SCOPE_AGENT);
          if (__all((int)(v >= tgt))) break;
          if (++guard > (1 << 20)) break;   // fail loud, not hung
        }
      }
      __syncthreads();

      // burst-gather h (16 rows x 512 u32 = 32KB) via 16B coherent loads
      const unsigned int* hin = hbuf + (size_t)(t & 1) * 65536 + (size_t)g * 8192;
      u32x4 wv[8];
      #pragma unroll
      for (int it = 0; it < 8; it++) {
        int fi = it * 1024 + tid * 4;
        const unsigned int* ap = hin + ((fi >> 9) * 512 + (fi & 511));
        asm volatile("global_load_dwordx4 %0, %1, off sc0 sc1"
                     : "=v"(wv[it]) : "v"(ap));
      }
      asm volatile("s_waitcnt vmcnt(0)" ::: "memory");
      __builtin_amdgcn_sched_barrier(0);
      #pragma unroll
      for (int it = 0; it < 8; it++) {
        int fi = it * 1024 + tid * 4;
        int row = fi >> 9, u0 = fi & 511;
        unsigned int h0 = (wv[it][0] & 0xffffu) | (wv[it][1] << 16);
        unsigned int h1 = (wv[it][2] & 0xffffu) | (wv[it][3] << 16);
        unsigned int l0 = (wv[it][0] >> 16) | (wv[it][1] & 0xffff0000u);
        unsigned int l1 = (wv[it][2] >> 16) | (wv[it][3] & 0xffff0000u);
        u32x2 hh = {h0, h1}, ll = {l0, l1};
        *(u32x2*)(Hhi + row * 520 + u0) = hh;
        *(u32x2*)(Hlo + row * 520 + u0) = ll;
      }
      __syncthreads();
    }

    // h-part GEMM: 3 independent accumulator chains
    f32x4 acc0 = {xpv[0], xpv[1], xpv[2], xpv[3]};
    f32x4 acc1 = {}, acc2 = {};
    if (t > 0) {
      #pragma unroll
      for (int s = 0; s < 16; s++) {
        bf16x8 Ah = *(const bf16x8*)(Hhi + ar + s * 32);
        bf16x8 Al = *(const bf16x8*)(Hlo + ar + s * 32);
        acc0 = __builtin_amdgcn_mfma_f32_16x16x32_bf16(Ah, Wh[s], acc0, 0, 0, 0);
        acc1 = __builtin_amdgcn_mfma_f32_16x16x32_bf16(Ah, Wl[s], acc1, 0, 0, 0);
        acc2 = __builtin_amdgcn_mfma_f32_16x16x32_bf16(Al, Wh[s], acc2, 0, 0, 0);
      }
    }

    // pointwise UR-LSTM update
    unsigned hw[4];
    float hf[4];
    const int base4 = lane & ~3;
    #pragma unroll
    for (int q = 0; q < 4; q++) {
      float a = acc0[q] + acc1[q] + acc2[q] + bv;
      float fv = __shfl(a, base4 + 0);
      float rv = __shfl(a, base4 + 1);
      float uv = __shfl(a, base4 + 2);
      float ov = __shfl(a, base4 + 3);
      float fg = sigm(fv + fbv);
      float rg = sigm(rv - fbv);
      float gg = 2.f * rg * fg + (1.f - 2.f * rg) * fg * fg;
      float cn = gg * c_st[q] + (1.f - gg) * tanh_(uv);
      float hn = sigm(ov) * tanh_(cn);
      c_st[q] = cn;
      hf[q] = hn;
      unsigned short hb = f2bf(hn);
      hw[q] = (unsigned)hb | ((unsigned)f2bf(hn - bf2f(hb)) << 16);
    }
    if ((lane & 3) == 0) {
      unsigned int* hout = hbuf + (size_t)((t + 1) & 1) * 65536;
      #pragma unroll
      for (int q = 0; q < 4; q++) {
        unsigned int* pp = hout + (size_t)(b0 + q) * 512 + u;
        asm volatile("global_store_dword %0, %1, off sc0 sc1"
                     :: "v"(pp), "v"(hw[q]) : "memory");
      }
      if (t == NT - 1) {
        #pragma unroll
        for (int q = 0; q < 4; q++) hT[(size_t)(b0 + q) * 512 + u] = hf[q];
      }
    }
    if (t != NT - 1) {
      asm volatile("s_waitcnt vmcnt(0)" ::: "memory");  // per-wave store drain
      __syncthreads();                                  // whole-WG drained
      if (tid == 0)
        __hip_atomic_store(flags + p, (unsigned)(t + 1), __ATOMIC_RELAXED,
                           __HIP_MEMORY_SCOPE_AGENT);
    }
  }
}

__global__ void __launch_bounds__(256, 1)
out_proj2(const unsigned char* __restrict__ ws, const float* __restrict__ Wout,
          const float* __restrict__ bout, float* __restrict__ out) {
  __shared__ float hrow[512];
  const float* hT = (const float*)(ws + WS_HT);
  const int b = blockIdx.x;
  const int o = threadIdx.x;
  for (int i = o; i < 512; i += 256) hrow[i] = hT[(size_t)b * 512 + i];
  __syncthreads();
  float acc = bout[o];
  const float4* w = (const float4*)(Wout + (size_t)o * 512);
  #pragma unroll 8
  for (int i = 0; i < 128; i++) {
    float4 wv = w[i];
    acc += hrow[4*i] * wv.x + hrow[4*i+1] * wv.y + hrow[4*i+2] * wv.z + hrow[4*i+3] * wv.w;
  }
  out[(size_t)b * 256 + o] = acc;
}

extern "C" void kernel_launch(void* const* d_in, const int* in_sizes, int n_in,
                              void* d_out, int out_size, void* d_ws, size_t ws_size,
                              hipStream_t stream) {
  const float* xs   = (const float*)d_in[0];
  const float* Wih  = (const float*)d_in[1];
  const float* Whh  = (const float*)d_in[2];
  const float* bias = (const float*)d_in[3];
  const float* fb   = (const float*)d_in[4];
  const float* Wout = (const float*)d_in[5];
  const float* bout = (const float*)d_in[6];
  unsigned char* ws = (unsigned char*)d_ws;
  float* out = (float*)d_out;

  hipMemsetAsync(ws, 0, 4096, stream);   // flag arrays

  unsigned short* whhp = (unsigned short*)(ws + WS_WHH);
  unsigned short* wihp = (unsigned short*)(ws + WS_WIH);
  unsigned char* xpo = ws + WS_XP;

  pack_whh_k<<<1024, 256, 0, stream>>>(Whh, whhp);
  pack_wih_k<<<1024, 256, 0, stream>>>(Wih, wihp);

  const size_t XPROJ_LDS = 2 * 64 * 520 * 2 + 4 * 32 * 36 * 4;  // 151552
  const size_t REC_LDS   = 2 * 16 * 520 * 2;                    // 33280

  if (ws_size >= WS_XP + XP32_BYTES) {
    xproj_gemm<false><<<1024, 256, XPROJ_LDS, stream>>>(xs, wihp, xpo);
    urlstm_rec2<false><<<256, 256, REC_LDS, stream>>>(whhp, xpo, bias, fb, ws);
  } else {
    xproj_gemm<true><<<1024, 256, XPROJ_LDS, stream>>>(xs, wihp, xpo);
    urlstm_rec2<true><<<256, 256, REC_LDS, stream>>>(whhp, xpo, bias, fb, ws);
  }
  out_proj2<<<128, 256, 0, stream>>>(ws, Wout, bout, out);
}